// Round 4
// baseline (380.206 us; speedup 1.0000x reference)
//
#include <hip/hip_runtime.h>

#define NF   16
#define C    8
#define NB   4
#define NPIX (512*512)
#define NBLKX 256
#define NBLK  (NBLKX * NB)   // 1024 blocks, must ALL be co-resident (4/CU @ 256 thr, VGPR<=128)
#define ITERS 4

// ws float layout:
//   [0,512)    sums[b][c*16+f]
//   [512,544)  counts[b*8+c]
//   [544]      barrier flag (int)
#define WS_CNT   512
#define WS_FLAG  544
#define WS_TOTAL 548

__global__ void init_kernel(float* __restrict__ ws, float* __restrict__ out) {
    int t = blockIdx.x * blockDim.x + threadIdx.x;
    if (t < WS_TOTAL) ws[t] = 0.0f;
    if (t == 0) out[0] = 0.0f;
}

// Single-pass fused kernel. Wave w owns features 4w..4w+3. Each thread holds
// 4 iters x 4 pixels x 4 features = 64 pred floats in registers across the
// device-wide barrier, so pred is read from global exactly ONCE.
__global__ __launch_bounds__(256, 4) void fused_kernel(const float* __restrict__ pred,
                                                       const int* __restrict__ tgt,
                                                       float* __restrict__ ws,
                                                       float* __restrict__ out) {
    __shared__ float s_part[4][256];
    __shared__ float s_raw[136];
    __shared__ float s_means[128];   // [f*8+c]
    __shared__ float s_inv;
    __shared__ float s_red[4];

    const int tid  = threadIdx.x;
    const int lane = tid & 63;
    const int wave = tid >> 6;          // 0..3
    const int b    = blockIdx.y;
    const int f0   = wave * 4;

    const float* predb = pred + (size_t)b * NF * NPIX;
    const int*   tgtb  = tgt  + (size_t)b * NPIX;

    float4 p[ITERS][4];
    int    labpack[ITERS];
    float  acc[4][C];
    float  cnt[C];
#pragma unroll
    for (int fi = 0; fi < 4; ++fi)
#pragma unroll
        for (int c = 0; c < C; ++c) acc[fi][c] = 0.0f;
#pragma unroll
    for (int c = 0; c < C; ++c) cnt[c] = 0.0f;

    // ---- phase 1: load once, masked sums ----
#pragma unroll
    for (int it = 0; it < ITERS; ++it) {
        const int base = (blockIdx.x * ITERS + it) * 256 + lane * 4;
        const int4 lb = *(const int4*)(tgtb + base);
        labpack[it] = lb.x | (lb.y << 8) | (lb.z << 16) | (lb.w << 24);
#pragma unroll
        for (int fi = 0; fi < 4; ++fi)
            p[it][fi] = *(const float4*)(predb + (f0 + fi) * NPIX + base);
#pragma unroll
        for (int c = 0; c < C; ++c) {
            const float mx = (lb.x == c) ? 1.0f : 0.0f;
            const float my = (lb.y == c) ? 1.0f : 0.0f;
            const float mz = (lb.z == c) ? 1.0f : 0.0f;
            const float mw = (lb.w == c) ? 1.0f : 0.0f;
#pragma unroll
            for (int fi = 0; fi < 4; ++fi)
                acc[fi][c] += mx * p[it][fi].x + my * p[it][fi].y
                            + mz * p[it][fi].z + mw * p[it][fi].w;
            if (wave == 0) cnt[c] += mx + my + mz + mw;
        }
    }

    // wave butterfly reduce; lane 0 commits (fire-and-forget atomics)
#pragma unroll
    for (int off = 32; off > 0; off >>= 1)
#pragma unroll
        for (int fi = 0; fi < 4; ++fi)
#pragma unroll
            for (int c = 0; c < C; ++c)
                acc[fi][c] += __shfl_down(acc[fi][c], off);
    if (wave == 0) {
#pragma unroll
        for (int off = 32; off > 0; off >>= 1)
#pragma unroll
            for (int c = 0; c < C; ++c) cnt[c] += __shfl_down(cnt[c], off);
    }
    if (lane == 0) {
        float* gsum = ws + b * (C * NF);
#pragma unroll
        for (int fi = 0; fi < 4; ++fi)
#pragma unroll
            for (int c = 0; c < C; ++c)
                atomicAdd(&gsum[c * NF + (f0 + fi)], acc[fi][c]);
        if (wave == 0) {
#pragma unroll
            for (int c = 0; c < C; ++c)
                atomicAdd(&ws[WS_CNT + b * C + c], cnt[c]);
        }
    }

    // ---- device-wide barrier (all 1024 blocks co-resident) ----
    __threadfence();
    __syncthreads();
    int* flag = (int*)(ws + WS_FLAG);
    if (tid == 0) {
        atomicAdd(flag, 1);
        while (__hip_atomic_load(flag, __ATOMIC_RELAXED, __HIP_MEMORY_SCOPE_AGENT) < NBLK)
            __builtin_amdgcn_s_sleep(32);
        __threadfence();
    }
    __syncthreads();

    // ---- means (atomic-reads: always coherent) ----
    if (tid < 136) {
        const int gidx = (tid < 128) ? (b * 128 + tid) : (WS_CNT + b * C + (tid - 128));
        s_raw[tid] = atomicAdd(&ws[gidx], 0.0f);
    }
    __syncthreads();
    if (tid < 128) {
        const int c = tid >> 4, f = tid & 15;
        s_means[f * C + c] = s_raw[c * NF + f] / s_raw[128 + c];
    }
    if (tid == 224) {
        float is = 0.0f;
#pragma unroll
        for (int c = 0; c < C; ++c) is += 1.0f / s_raw[128 + c];
        s_inv = is;
    }
    __syncthreads();

    // ---- phase 2: distances from registers, cross-wave feature combine in LDS ----
    float accd = 0.0f;
#pragma unroll
    for (int it = 0; it < ITERS; ++it) {
        const int lp = labpack[it];
        const int c0 = lp & 0xff, c1 = (lp >> 8) & 0xff,
                  c2 = (lp >> 16) & 0xff, c3 = (lp >> 24) & 0xff;
        float s0 = 0.f, s1 = 0.f, s2 = 0.f, s3 = 0.f;
#pragma unroll
        for (int fi = 0; fi < 4; ++fi) {
            const int fb = (f0 + fi) * C;
            float d0 = s_means[fb + c0] - p[it][fi].x;
            float d1 = s_means[fb + c1] - p[it][fi].y;
            float d2 = s_means[fb + c2] - p[it][fi].z;
            float d3 = s_means[fb + c3] - p[it][fi].w;
            s0 += d0 * d0; s1 += d1 * d1; s2 += d2 * d2; s3 += d3 * d3;
        }
        s_part[wave][lane * 4 + 0] = s0;
        s_part[wave][lane * 4 + 1] = s1;
        s_part[wave][lane * 4 + 2] = s2;
        s_part[wave][lane * 4 + 3] = s3;
        __syncthreads();
        float tot = s_part[0][tid] + s_part[1][tid] + s_part[2][tid] + s_part[3][tid];
        float t = fminf(fmaxf(sqrtf(tot) - 0.5f, 0.0f), 100000.0f);
        accd += t * t;
        __syncthreads();
    }

#pragma unroll
    for (int off = 32; off > 0; off >>= 1) accd += __shfl_down(accd, off);
    if (lane == 0) s_red[wave] = accd;
    __syncthreads();
    if (tid == 0)
        atomicAdd(out, (s_red[0] + s_red[1] + s_red[2] + s_red[3]) * s_inv * 0.125f);
}

extern "C" void kernel_launch(void* const* d_in, const int* in_sizes, int n_in,
                              void* d_out, int out_size, void* d_ws, size_t ws_size,
                              hipStream_t stream) {
    const float* pred = (const float*)d_in[0];
    const int*   tgt  = (const int*)d_in[1];
    float* out = (float*)d_out;
    float* ws  = (float*)d_ws;

    init_kernel<<<dim3((WS_TOTAL + 255) / 256), dim3(256), 0, stream>>>(ws, out);
    fused_kernel<<<dim3(NBLKX, NB), dim3(256), 0, stream>>>(pred, tgt, ws, out);
}

// Round 5
// 371.126 us; speedup vs baseline: 1.0245x; 1.0245x over previous
//
#include <hip/hip_runtime.h>

#define NF   16
#define C    8
#define NB   4
#define NPIX (512*512)
#define NBLKX 256
#define NBLK  (NBLKX * NB)   // 1024 blocks, all co-resident (4/CU @ 256 thr, VGPR<=128, LDS<=40KB)
#define ITERS 4
#define RITERS 2             // iterations kept in registers; rest parked in LDS

// ws float layout:
//   [0,512)    sums[b][c*16+f]
//   [512,544)  counts[b*8+c]
//   [544]      barrier flag (int)
#define WS_CNT   512
#define WS_FLAG  544
#define WS_TOTAL 548

__global__ void init_kernel(float* __restrict__ ws, float* __restrict__ out) {
    int t = blockIdx.x * blockDim.x + threadIdx.x;
    if (t < WS_TOTAL) ws[t] = 0.0f;
    if (t == 0) out[0] = 0.0f;
}

// Single-pass fused kernel. Wave w owns features 4w..4w+3. Each thread's 64
// pred floats live across the device barrier as 32 VGPRs + 32 B*4 in LDS
// (LDS used as manual spill: each wave reads back its own slots, no sharing).
__global__ __launch_bounds__(256, 4) void fused_kernel(const float* __restrict__ pred,
                                                       const int* __restrict__ tgt,
                                                       float* __restrict__ ws,
                                                       float* __restrict__ out) {
    __shared__ float4 s_data4[ITERS - RITERS][NF][64];   // 32 KB parked pred data
    __shared__ float4 s_part4[4][64];                    // cross-wave norm combine
    __shared__ float  s_raw[136];
    __shared__ float  s_means[128];                      // [f*8+c]
    __shared__ float  s_inv;
    __shared__ float  s_red[4];

    const int tid  = threadIdx.x;
    const int lane = tid & 63;
    const int wave = tid >> 6;          // 0..3
    const int b    = blockIdx.y;
    const int f0   = wave * 4;

    const float* predb = pred + (size_t)b * NF * NPIX;
    const int*   tgtb  = tgt  + (size_t)b * NPIX;

    float4 p[RITERS][4];
    int    labpack[ITERS];
    float  acc[4][C];
    float  cnt[C];
#pragma unroll
    for (int fi = 0; fi < 4; ++fi)
#pragma unroll
        for (int c = 0; c < C; ++c) acc[fi][c] = 0.0f;
#pragma unroll
    for (int c = 0; c < C; ++c) cnt[c] = 0.0f;

    // ---- phase 1: load once, masked sums; retain data in regs/LDS ----
#pragma unroll
    for (int it = 0; it < ITERS; ++it) {
        const int base = (blockIdx.x * ITERS + it) * 256 + lane * 4;
        const int4 lb = *(const int4*)(tgtb + base);
        labpack[it] = lb.x | (lb.y << 8) | (lb.z << 16) | (lb.w << 24);
        float4 q[4];
#pragma unroll
        for (int fi = 0; fi < 4; ++fi)
            q[fi] = *(const float4*)(predb + (f0 + fi) * NPIX + base);
#pragma unroll
        for (int c = 0; c < C; ++c) {
            const float mx = (lb.x == c) ? 1.0f : 0.0f;
            const float my = (lb.y == c) ? 1.0f : 0.0f;
            const float mz = (lb.z == c) ? 1.0f : 0.0f;
            const float mw = (lb.w == c) ? 1.0f : 0.0f;
#pragma unroll
            for (int fi = 0; fi < 4; ++fi)
                acc[fi][c] += mx * q[fi].x + my * q[fi].y + mz * q[fi].z + mw * q[fi].w;
            if (wave == 0) cnt[c] += mx + my + mz + mw;
        }
        if (it < RITERS) {
#pragma unroll
            for (int fi = 0; fi < 4; ++fi) p[it][fi] = q[fi];
        } else {
#pragma unroll
            for (int fi = 0; fi < 4; ++fi) s_data4[it - RITERS][f0 + fi][lane] = q[fi];
        }
    }

    // wave butterfly reduce; lane 0 commits
#pragma unroll
    for (int off = 32; off > 0; off >>= 1)
#pragma unroll
        for (int fi = 0; fi < 4; ++fi)
#pragma unroll
            for (int c = 0; c < C; ++c)
                acc[fi][c] += __shfl_down(acc[fi][c], off);
    if (wave == 0) {
#pragma unroll
        for (int off = 32; off > 0; off >>= 1)
#pragma unroll
            for (int c = 0; c < C; ++c) cnt[c] += __shfl_down(cnt[c], off);
    }
    if (lane == 0) {
        float* gsum = ws + b * (C * NF);
#pragma unroll
        for (int fi = 0; fi < 4; ++fi)
#pragma unroll
            for (int c = 0; c < C; ++c)
                atomicAdd(&gsum[c * NF + (f0 + fi)], acc[fi][c]);
        if (wave == 0) {
#pragma unroll
            for (int c = 0; c < C; ++c)
                atomicAdd(&ws[WS_CNT + b * C + c], cnt[c]);
        }
    }

    // ---- device-wide barrier (all 1024 blocks co-resident) ----
    __threadfence();
    __syncthreads();
    int* flag = (int*)(ws + WS_FLAG);
    if (tid == 0) {
        atomicAdd(flag, 1);
        while (__hip_atomic_load(flag, __ATOMIC_RELAXED, __HIP_MEMORY_SCOPE_AGENT) < NBLK)
            __builtin_amdgcn_s_sleep(32);
        __threadfence();
    }
    __syncthreads();

    // ---- means (atomic-reads: coherent across XCDs) ----
    if (tid < 136) {
        const int gidx = (tid < 128) ? (b * 128 + tid) : (WS_CNT + b * C + (tid - 128));
        s_raw[tid] = atomicAdd(&ws[gidx], 0.0f);
    }
    __syncthreads();
    if (tid < 128) {
        const int c = tid >> 4, f = tid & 15;
        s_means[f * C + c] = s_raw[c * NF + f] / s_raw[128 + c];
    }
    if (tid == 224) {
        float is = 0.0f;
#pragma unroll
        for (int c = 0; c < C; ++c) is += 1.0f / s_raw[128 + c];
        s_inv = is;
    }
    __syncthreads();

    // ---- phase 2: distances from retained data ----
    float accd = 0.0f;
#pragma unroll
    for (int it = 0; it < ITERS; ++it) {
        const int lp = labpack[it];
        const int c0 = lp & 0xff, c1 = (lp >> 8) & 0xff,
                  c2 = (lp >> 16) & 0xff, c3 = (lp >> 24) & 0xff;
        float s0 = 0.f, s1 = 0.f, s2 = 0.f, s3 = 0.f;
#pragma unroll
        for (int fi = 0; fi < 4; ++fi) {
            const float4 q = (it < RITERS) ? p[it][fi] : s_data4[it - RITERS][f0 + fi][lane];
            const int fb = (f0 + fi) * C;
            float d0 = s_means[fb + c0] - q.x;
            float d1 = s_means[fb + c1] - q.y;
            float d2 = s_means[fb + c2] - q.z;
            float d3 = s_means[fb + c3] - q.w;
            s0 += d0 * d0; s1 += d1 * d1; s2 += d2 * d2; s3 += d3 * d3;
        }
        s_part4[wave][lane] = make_float4(s0, s1, s2, s3);
        __syncthreads();
        float tot = 0.0f;
#pragma unroll
        for (int w = 0; w < 4; ++w) {
            const float* pp = (const float*)&s_part4[w][tid >> 2];
            tot += pp[tid & 3];
        }
        float t = fminf(fmaxf(sqrtf(tot) - 0.5f, 0.0f), 100000.0f);
        accd += t * t;
        __syncthreads();
    }

#pragma unroll
    for (int off = 32; off > 0; off >>= 1) accd += __shfl_down(accd, off);
    if (lane == 0) s_red[wave] = accd;
    __syncthreads();
    if (tid == 0)
        atomicAdd(out, (s_red[0] + s_red[1] + s_red[2] + s_red[3]) * s_inv * 0.125f);
}

extern "C" void kernel_launch(void* const* d_in, const int* in_sizes, int n_in,
                              void* d_out, int out_size, void* d_ws, size_t ws_size,
                              hipStream_t stream) {
    const float* pred = (const float*)d_in[0];
    const int*   tgt  = (const int*)d_in[1];
    float* out = (float*)d_out;
    float* ws  = (float*)d_ws;

    init_kernel<<<dim3((WS_TOTAL + 255) / 256), dim3(256), 0, stream>>>(ws, out);
    fused_kernel<<<dim3(NBLKX, NB), dim3(256), 0, stream>>>(pred, tgt, ws, out);
}

// Round 6
// 351.858 us; speedup vs baseline: 1.0806x; 1.0548x over previous
//
#include <hip/hip_runtime.h>

#define NF   16
#define C    8
#define NB   4
#define NPIX (512*512)
#define NBLKX 256
#define NBLK  (NBLKX * NB)   // 1024 blocks, all co-resident (4/CU: LDS 34.4KB, VGPR<=128)
#define PXB  1024            // pixels per block
#define ITERS 4              // 4 iters x 256 px

// ws float layout:
//   [0,512)    sums[b][c*16+f]
//   [512,544)  counts[b*8+c]
//   [544]      barrier flag (int)
#define WS_CNT   512
#define WS_FLAG  544
#define WS_TOTAL 548

__global__ void init_kernel(float* __restrict__ ws, float* __restrict__ out) {
    int t = blockIdx.x * blockDim.x + threadIdx.x;
    if (t < WS_TOTAL) ws[t] = 0.0f;
    if (t == 0) out[0] = 0.0f;
}

__device__ inline unsigned bf16pack2(float a, float b) {   // RTNE bf16 pair
    unsigned ua = __float_as_uint(a); ua = (ua + 0x7FFFu + ((ua >> 16) & 1u)) >> 16;
    unsigned ub = __float_as_uint(b); ub = (ub + 0x7FFFu + ((ub >> 16) & 1u)) >> 16;
    return ua | (ub << 16);
}
__device__ inline float bf16lo(unsigned u) { return __uint_as_float(u << 16); }
__device__ inline float bf16hi(unsigned u) { return __uint_as_float(u & 0xFFFF0000u); }

// Single-pass fused kernel, ZERO per-thread retention across the barrier:
// all pixel data parked in LDS as bf16 [f][px] (32 KB) + packed labels (1 KB).
// Wave w computes masked sums for features 4w..4w+3; phase 2 reads back from LDS.
__global__ __launch_bounds__(256, 4) void fused_kernel(const float* __restrict__ pred,
                                                       const int* __restrict__ tgt,
                                                       float* __restrict__ ws,
                                                       float* __restrict__ out) {
    __shared__ unsigned s_pred[NF * PXB / 2];   // bf16 pairs, [f][px]: 32 KB
    __shared__ unsigned s_lab[PXB / 4];         // packed labels, 1 KB
    __shared__ float    s_raw[136];
    __shared__ float    s_means[128];           // [f*8+c]
    __shared__ float    s_inv;
    __shared__ float    s_red[4];

    const int tid  = threadIdx.x;
    const int lane = tid & 63;
    const int wave = tid >> 6;          // 0..3
    const int b    = blockIdx.y;
    const int f0   = wave * 4;
    const int px0  = blockIdx.x * PXB;  // block-global pixel base

    const float* predb = pred + (size_t)b * NF * NPIX;
    const int*   tgtb  = tgt  + (size_t)b * NPIX;

    // ---- labels: wave 0 loads once, packs to LDS, counts ----
    float cnt[C];
#pragma unroll
    for (int c = 0; c < C; ++c) cnt[c] = 0.0f;
    if (wave == 0) {
#pragma unroll
        for (int it = 0; it < ITERS; ++it) {
            int4 lb = *(const int4*)(tgtb + px0 + it * 256 + lane * 4);
            s_lab[it * 64 + lane] = (unsigned)(lb.x | (lb.y << 8) | (lb.z << 16) | (lb.w << 24));
#pragma unroll
            for (int c = 0; c < C; ++c)
                cnt[c] += (lb.x == c ? 1.f : 0.f) + (lb.y == c ? 1.f : 0.f)
                        + (lb.z == c ? 1.f : 0.f) + (lb.w == c ? 1.f : 0.f);
        }
    }
    __syncthreads();

    // ---- phase 1: load pred once, masked sums, park bf16 in LDS ----
    float acc[4][C];
#pragma unroll
    for (int fi = 0; fi < 4; ++fi)
#pragma unroll
        for (int c = 0; c < C; ++c) acc[fi][c] = 0.0f;

#pragma unroll
    for (int it = 0; it < ITERS; ++it) {
        const int pxi = it * 256 + lane * 4;    // block-local pixel
        float4 q[4];
#pragma unroll
        for (int fi = 0; fi < 4; ++fi)
            q[fi] = *(const float4*)(predb + (size_t)(f0 + fi) * NPIX + px0 + pxi);
        const unsigned lp = s_lab[it * 64 + lane];
        const int c0 = lp & 255, c1 = (lp >> 8) & 255, c2 = (lp >> 16) & 255, c3 = lp >> 24;
#pragma unroll
        for (int c = 0; c < C; ++c) {
            const float mx = (c0 == c) ? 1.f : 0.f;
            const float my = (c1 == c) ? 1.f : 0.f;
            const float mz = (c2 == c) ? 1.f : 0.f;
            const float mw = (c3 == c) ? 1.f : 0.f;
#pragma unroll
            for (int fi = 0; fi < 4; ++fi)
                acc[fi][c] += mx * q[fi].x + my * q[fi].y + mz * q[fi].z + mw * q[fi].w;
        }
        // park: contiguous 512B per wave-store -> conflict-minimal
#pragma unroll
        for (int fi = 0; fi < 4; ++fi) {
            uint2 pk = make_uint2(bf16pack2(q[fi].x, q[fi].y), bf16pack2(q[fi].z, q[fi].w));
            *(uint2*)&s_pred[((f0 + fi) * PXB + pxi) >> 1] = pk;
        }
    }

    // wave butterfly reduce; lane 0 commits partial sums
#pragma unroll
    for (int off = 32; off > 0; off >>= 1)
#pragma unroll
        for (int fi = 0; fi < 4; ++fi)
#pragma unroll
            for (int c = 0; c < C; ++c)
                acc[fi][c] += __shfl_down(acc[fi][c], off);
    if (wave == 0) {
#pragma unroll
        for (int off = 32; off > 0; off >>= 1)
#pragma unroll
            for (int c = 0; c < C; ++c) cnt[c] += __shfl_down(cnt[c], off);
    }
    if (lane == 0) {
        float* gsum = ws + b * (C * NF);
#pragma unroll
        for (int fi = 0; fi < 4; ++fi)
#pragma unroll
            for (int c = 0; c < C; ++c)
                atomicAdd(&gsum[c * NF + (f0 + fi)], acc[fi][c]);
        if (wave == 0) {
#pragma unroll
            for (int c = 0; c < C; ++c)
                atomicAdd(&ws[WS_CNT + b * C + c], cnt[c]);
        }
    }

    // ---- device-wide barrier (all 1024 blocks co-resident) ----
    __threadfence();
    __syncthreads();
    int* flag = (int*)(ws + WS_FLAG);
    if (tid == 0) {
        atomicAdd(flag, 1);
        while (__hip_atomic_load(flag, __ATOMIC_RELAXED, __HIP_MEMORY_SCOPE_AGENT) < NBLK)
            __builtin_amdgcn_s_sleep(32);
        __threadfence();
    }
    __syncthreads();

    // ---- means (atomic-reads: coherent across XCDs) ----
    if (tid < 136) {
        const int gidx = (tid < 128) ? (b * 128 + tid) : (WS_CNT + b * C + (tid - 128));
        s_raw[tid] = atomicAdd(&ws[gidx], 0.0f);
    }
    __syncthreads();
    if (tid < 128) {
        const int c = tid >> 4, f = tid & 15;
        s_means[f * C + c] = s_raw[c * NF + f] / s_raw[128 + c];
    }
    if (tid == 224) {
        float is = 0.0f;
#pragma unroll
        for (int c = 0; c < C; ++c) is += 1.0f / s_raw[128 + c];
        s_inv = is;
    }
    __syncthreads();

    // ---- phase 2: thread t owns pixels 4t..4t+3, reads pred back from LDS ----
    const unsigned labd = s_lab[tid];
    const int c0 = labd & 255, c1 = (labd >> 8) & 255, c2 = (labd >> 16) & 255, c3 = labd >> 24;
    float s0 = 0.f, s1 = 0.f, s2 = 0.f, s3 = 0.f;
#pragma unroll
    for (int f = 0; f < NF; ++f) {
        uint2 hv = *(const uint2*)&s_pred[f * (PXB / 2) + tid * 2];
        float d0 = s_means[f * C + c0] - bf16lo(hv.x);
        float d1 = s_means[f * C + c1] - bf16hi(hv.x);
        float d2 = s_means[f * C + c2] - bf16lo(hv.y);
        float d3 = s_means[f * C + c3] - bf16hi(hv.y);
        s0 += d0 * d0; s1 += d1 * d1; s2 += d2 * d2; s3 += d3 * d3;
    }
    float t0 = fminf(fmaxf(sqrtf(s0) - 0.5f, 0.0f), 100000.0f);
    float t1 = fminf(fmaxf(sqrtf(s1) - 0.5f, 0.0f), 100000.0f);
    float t2 = fminf(fmaxf(sqrtf(s2) - 0.5f, 0.0f), 100000.0f);
    float t3 = fminf(fmaxf(sqrtf(s3) - 0.5f, 0.0f), 100000.0f);
    float accd = t0 * t0 + t1 * t1 + t2 * t2 + t3 * t3;

#pragma unroll
    for (int off = 32; off > 0; off >>= 1) accd += __shfl_down(accd, off);
    if (lane == 0) s_red[wave] = accd;
    __syncthreads();
    if (tid == 0)
        atomicAdd(out, (s_red[0] + s_red[1] + s_red[2] + s_red[3]) * s_inv * 0.125f);
}

extern "C" void kernel_launch(void* const* d_in, const int* in_sizes, int n_in,
                              void* d_out, int out_size, void* d_ws, size_t ws_size,
                              hipStream_t stream) {
    const float* pred = (const float*)d_in[0];
    const int*   tgt  = (const int*)d_in[1];
    float* out = (float*)d_out;
    float* ws  = (float*)d_ws;

    init_kernel<<<dim3((WS_TOTAL + 255) / 256), dim3(256), 0, stream>>>(ws, out);
    fused_kernel<<<dim3(NBLKX, NB), dim3(256), 0, stream>>>(pred, tgt, ws, out);
}